// Round 11
// baseline (327.051 us; speedup 1.0000x reference)
//
#include <hip/hip_runtime.h>

#define NODES 50000
#define EDGES 800000
#define FIN 128
#define DIM 256
#define GRAPHS 256
#define PAD_M 50048   // 782 * 64
#define PRESCALE_BLOCKS (NODES * FIN / 4 / 256) // 6250 exact
#define HBLOCKS 256                             // histogram copies / edge chunks
#define CHUNK (EDGES / HBLOCKS)                 // 3125 edges per block, exact
#define HALF_N 25000                            // nodes per LDS half
#define HALF_W 12500                            // u32 words per half (2 nodes/u32)
#define RB 98                                   // reduce/scan blocks (512 nodes each)

typedef short short8 __attribute__((ext_vector_type(8)));
typedef float f32x4 __attribute__((ext_vector_type(4)));

__device__ __forceinline__ float bf2f(uint u) { return __uint_as_float(u << 16); }
__device__ __forceinline__ ushort f2bf(float f) {
    uint b = __float_as_uint(f);
    return (ushort)((b + 0x7FFF + ((b >> 16) & 1)) >> 16);
}

// Both histograms in ONE dispatch: blocks [0,256) dst->histIn, [256,512) src->histOut.
// Also zeroes norm_sum for this launch. Streaming dump, no global atomics.
__global__ __launch_bounds__(256) void hist2_kernel(const int* __restrict__ src,
                                                    const int* __restrict__ dst,
                                                    uint* __restrict__ histIn,
                                                    uint* __restrict__ histOut,
                                                    float* __restrict__ norm_sum) {
    __shared__ uint cur[HALF_W];
    if (blockIdx.x == 0 && threadIdx.x == 0) *norm_sum = 0.0f;
    int b = blockIdx.x & 255, tid = threadIdx.x;
    const int* idx = (blockIdx.x < HBLOCKS) ? dst : src;
    uint* histG    = (blockIdx.x < HBLOCKS) ? histIn : histOut;
    int base = b * CHUNK;
    for (int half = 0; half < 2; ++half) {
        for (int j = tid; j < HALF_W; j += 256) cur[j] = 0;
        __syncthreads();
        int lo = half * HALF_N;
        for (int e = base + tid; e < base + CHUNK; e += 256) {
            int local = idx[e] - lo;
            if ((unsigned)local < (unsigned)HALF_N)
                atomicAdd(&cur[local >> 1], 1u << ((local & 1) * 16));
        }
        __syncthreads();
        uint* dstp = histG + (size_t)b * (2 * HALF_W) + half * HALF_W;
        for (int j = tid; j < HALF_W; j += 256) dstp[j] = cur[j];
        __syncthreads();
    }
}

// Sum the 256 copies -> deg_in / norms; in-place transform histIn into per-block
// EXCLUSIVE prefixes (packed u16); emit per-512-node block sums.
__global__ __launch_bounds__(256) void reduce_hist_kernel(uint* __restrict__ histIn,
                                                          const uint* __restrict__ histOut,
                                                          int* __restrict__ deg_in,
                                                          float* __restrict__ in_norm,
                                                          float* __restrict__ out_norm,
                                                          int* __restrict__ block_sums) {
    __shared__ int red[4];
    int t32 = blockIdx.x * 256 + threadIdx.x;
    uint lo = 0, hi = 0;
    if (t32 < 2 * HALF_W) {
#pragma unroll 4
        for (int c = 0; c < HBLOCKS; ++c) {
            size_t a = (size_t)c * (2 * HALF_W) + t32;
            uint u = histIn[a];
            histIn[a] = lo | (hi << 16);       // exclusive prefix over blocks
            lo += u & 0xFFFFu;
            hi += u >> 16;
        }
        uint olo = 0, ohi = 0;
#pragma unroll 4
        for (int c = 0; c < HBLOCKS; ++c) {
            uint u = histOut[(size_t)c * (2 * HALF_W) + t32];
            olo += u & 0xFFFFu;
            ohi += u >> 16;
        }
        int n0 = 2 * t32;
        deg_in[n0]     = (int)lo;
        deg_in[n0 + 1] = (int)hi;
        in_norm[n0]      = rsqrtf(fmaxf((float)lo, 1.0f));
        in_norm[n0 + 1]  = rsqrtf(fmaxf((float)hi, 1.0f));
        out_norm[n0]     = rsqrtf(fmaxf((float)olo, 1.0f));
        out_norm[n0 + 1] = rsqrtf(fmaxf((float)ohi, 1.0f));
    }
    int s = (int)(lo + hi);
    int wave = threadIdx.x >> 6, lane = threadIdx.x & 63;
#pragma unroll
    for (int off = 32; off > 0; off >>= 1) s += __shfl_down(s, off);
    if (lane == 0) red[wave] = s;
    __syncthreads();
    if (threadIdx.x == 0) block_sums[blockIdx.x] = red[0] + red[1] + red[2] + red[3];
}

// Fused: [scan-final (incl. inline 98-value blocksum scan) | prescale xs | W1T | W2T].
__global__ __launch_bounds__(256) void scanfinal_prep_kernel(const int* __restrict__ deg,
                                                             const int* __restrict__ block_sums,
                                                             int* __restrict__ row_start,
                                                             const float* __restrict__ x,
                                                             const float* __restrict__ out_norm,
                                                             ushort* __restrict__ xs,
                                                             const float* __restrict__ W1,
                                                             ushort* __restrict__ W1T,
                                                             const float* __restrict__ W2,
                                                             ushort* __restrict__ W2T) {
    __shared__ int s[256];
    int b = blockIdx.x, t = threadIdx.x;
    if (b < RB) {
        // inline exclusive scan of the RB block sums (redundant per block, 98 ints)
        s[t] = (t < RB) ? block_sums[t] : 0;
        __syncthreads();
#pragma unroll
        for (int off = 1; off < 256; off <<= 1) {
            int u = (t >= off) ? s[t - off] : 0;
            __syncthreads();
            s[t] += u;
            __syncthreads();
        }
        int block_off = (b == 0) ? 0 : s[b - 1];
        if (b == 0 && t == 0) row_start[NODES] = s[RB - 1];   // total = EDGES
        __syncthreads();
        // exclusive scan of this block's 512 degrees (2 per thread)
        int i0 = b * 512 + 2 * t;
        int v0 = (i0 < NODES) ? deg[i0] : 0;
        int v1 = (i0 + 1 < NODES) ? deg[i0 + 1] : 0;
        int pair = v0 + v1;
        s[t] = pair;
        __syncthreads();
#pragma unroll
        for (int off = 1; off < 256; off <<= 1) {
            int u = (t >= off) ? s[t - off] : 0;
            __syncthreads();
            s[t] += u;
            __syncthreads();
        }
        int excl = block_off + s[t] - pair;
        if (i0 < NODES) row_start[i0] = excl;
        if (i0 + 1 < NODES) row_start[i0 + 1] = excl + v0;
    } else if (b < RB + PRESCALE_BLOCKS) {
        int i = (b - RB) * 256 + t;               // < NODES*FIN/4
        int row = i >> 5;                         // FIN/4 = 32 float4 per row
        float on = out_norm[row];
        float4 v = ((const float4*)x)[i];
        ushort4 o;
        o.x = f2bf(v.x * on); o.y = f2bf(v.y * on);
        o.z = f2bf(v.z * on); o.w = f2bf(v.w * on);
        ((ushort4*)xs)[i] = o;
    } else if (b < RB + PRESCALE_BLOCKS + FIN * DIM / 256) {
        int i = (b - RB - PRESCALE_BLOCKS) * 256 + t;   // < 32768
        int n = i >> 7, k = i & 127;
        W1T[i] = f2bf(W1[(size_t)k * DIM + n]);
    } else {
        int i = (b - RB - PRESCALE_BLOCKS - FIN * DIM / 256) * 256 + t;  // < 65536
        int n = i >> 8, k = i & 255;
        W2T[i] = f2bf(W2[(size_t)k * DIM + n]);
    }
}

// Scatter with LDS cursors seeded from the per-block exclusive prefixes.
__global__ __launch_bounds__(256) void scatter_lds_kernel(const int* __restrict__ src,
                                                          const int* __restrict__ dst,
                                                          const uint* __restrict__ histIn,
                                                          const int* __restrict__ row_start,
                                                          int* __restrict__ src_sorted) {
    __shared__ uint cur[HALF_W];
    int b = blockIdx.x, tid = threadIdx.x;
    int base = b * CHUNK;
    for (int half = 0; half < 2; ++half) {
        const uint* offp = histIn + (size_t)b * (2 * HALF_W) + half * HALF_W;
        for (int j = tid; j < HALF_W; j += 256) cur[j] = offp[j];
        __syncthreads();
        int lo = half * HALF_N;
        for (int e = base + tid; e < base + CHUNK; e += 256) {
            int d = dst[e];
            int local = d - lo;
            if ((unsigned)local < (unsigned)HALF_N) {
                int sel = (local & 1) * 16;
                uint old = atomicAdd(&cur[local >> 1], 1u << sel);
                int pos = row_start[d] + (int)((old >> sel) & 0xFFFFu);
                src_sorted[pos] = src[e];
            }
        }
        __syncthreads();
    }
}

// Fused aggregate + MFMA GEMM: one kernel per layer.
// Block = 64 output rows. Phase 1: 4 waves aggregate 16 nodes each (8-edge
// unroll gather, the measured-roofline form) into a padded LDS A-tile (bf16).
// Phase 2: MFMA from LDS (2-way bank alias only = free) with W from global.
// MFMA compute of blocks in phase 2 overlaps other blocks' phase-1 gathers.
// MODE 0: out bf16 = relu(acc+bias)*scale[row]; MODE 1: out bf16 = acc+bias
// with fused row-L2-norm accumulation into norm_sum.
template<int K, int MODE>
__global__ __launch_bounds__(256) void gemm_agg_kernel(const ushort* __restrict__ in,
                                                       const int* __restrict__ row_start,
                                                       const int* __restrict__ src_sorted,
                                                       const float* __restrict__ in_norm,
                                                       const ushort* __restrict__ WT,
                                                       const float* __restrict__ bias,
                                                       ushort* __restrict__ Cout,
                                                       const float* __restrict__ scale,
                                                       float* __restrict__ norm_sum,
                                                       int M) {
    constexpr int LK = K + 8;            // padded LDS row stride (shorts, 16B mult)
    __shared__ ushort At[64][LK];
    __shared__ float rowsq[4][64];
    constexpr int VPL = K / 64;          // bf16 per lane (2 or 4)
    constexpr int NU = VPL / 2;          // dwords per lane
    int lane = threadIdx.x & 63, wave = threadIdx.x >> 6;
    int m0 = blockIdx.x * 64;
    // ---- Phase 1: aggregate ----
    int off = lane * VPL;
    for (int r = 0; r < 16; ++r) {
        int node = m0 + wave * 16 + r;
        float acc[VPL] = {};
        if (node < NODES) {
            int e0 = row_start[node], e1 = row_start[node + 1];
            int niter = (e1 - e0 + 7) >> 3;
            for (int it = 0; it < niter; ++it) {
                int eb = e0 + it * 8;
                int idx[8];
#pragma unroll
                for (int j = 0; j < 8; ++j) idx[j] = src_sorted[min(eb + j, e1 - 1)];
                uint u[8][NU];
#pragma unroll
                for (int j = 0; j < 8; ++j) {
                    const uint* p = (const uint*)(in + (size_t)idx[j] * K + off);
#pragma unroll
                    for (int q = 0; q < NU; ++q) u[j][q] = p[q];
                }
#pragma unroll
                for (int j = 0; j < 8; ++j) {
                    uint ok = (eb + j < e1) ? 0xFFFFFFFFu : 0u;
#pragma unroll
                    for (int q = 0; q < NU; ++q) {
                        uint uu = u[j][q] & ok;
                        acc[2*q]   += bf2f(uu & 0xFFFFu);
                        acc[2*q+1] += bf2f(uu >> 16);
                    }
                }
            }
            float inn = in_norm[node];
#pragma unroll
            for (int v = 0; v < VPL; ++v) acc[v] *= inn;
        }
        uint* po = (uint*)&At[wave * 16 + r][off];
#pragma unroll
        for (int q = 0; q < NU; ++q)
            po[q] = (uint)f2bf(acc[2*q]) | ((uint)f2bf(acc[2*q+1]) << 16);
    }
    __syncthreads();
    // ---- Phase 2: MFMA ----
    int n0 = wave * 64;
    int ll = lane & 15, lh = lane >> 4;
    f32x4 acc[4][4] = {};
    const ushort* Bb = WT + (size_t)(n0 + ll) * K + lh * 8;
#pragma unroll
    for (int k0 = 0; k0 < K; k0 += 32) {
        short8 a[4], b[4];
#pragma unroll
        for (int mi = 0; mi < 4; ++mi) a[mi] = *(const short8*)&At[mi * 16 + ll][k0 + lh * 8];
#pragma unroll
        for (int ni = 0; ni < 4; ++ni) b[ni] = *(const short8*)(Bb + (size_t)ni * 16 * K + k0);
#pragma unroll
        for (int mi = 0; mi < 4; ++mi)
#pragma unroll
            for (int ni = 0; ni < 4; ++ni)
                acc[mi][ni] = __builtin_amdgcn_mfma_f32_16x16x32_bf16(a[mi], b[ni], acc[mi][ni], 0, 0, 0);
    }
#pragma unroll
    for (int mi = 0; mi < 4; ++mi) {
#pragma unroll
        for (int r = 0; r < 4; ++r) {
            int row = m0 + mi * 16 + lh * 4 + r;
            float sc = (MODE == 0 && row < M) ? scale[row] : 1.0f;
            float p = 0.0f;
#pragma unroll
            for (int ni = 0; ni < 4; ++ni) {
                int col = n0 + ni * 16 + ll;
                float v = acc[mi][ni][r] + bias[col];
                if (MODE == 0) v = fmaxf(v, 0.0f) * sc;
                else p += v * v;
                if (row < M) Cout[(size_t)row * DIM + col] = f2bf(v);
            }
            if (MODE == 1) {
#pragma unroll
                for (int m = 1; m < 16; m <<= 1) p += __shfl_xor(p, m);
                if (ll == 0) rowsq[wave][mi * 16 + lh * 4 + r] = p;
            }
        }
    }
    if (MODE == 1) {
        __syncthreads();
        if (threadIdx.x < 64) {
            int lr = threadIdx.x;
            float s = rowsq[0][lr] + rowsq[1][lr] + rowsq[2][lr] + rowsq[3][lr];
            float l = (m0 + lr < M) ? sqrtf(s) : 0.0f;
#pragma unroll
            for (int m = 32; m > 0; m >>= 1) l += __shfl_down(l, m);
            if (lr == 0) atomicAdd(norm_sum, l);
        }
    }
}

// One block per graph (n2g is sorted): binary-search node range, no atomics.
__global__ __launch_bounds__(256) void pool_kernel(const ushort* __restrict__ h2,
                                                   const int* __restrict__ n2g,
                                                   const float* __restrict__ norm_sum,
                                                   float* __restrict__ out) {
    int g = blockIdx.x, f = threadIdx.x;
    int lo = 0, hi = NODES;
    while (lo < hi) { int mid = (lo + hi) >> 1; if (n2g[mid] < g) lo = mid + 1; else hi = mid; }
    int start = lo;
    hi = NODES;
    while (lo < hi) { int mid = (lo + hi) >> 1; if (n2g[mid] < g + 1) lo = mid + 1; else hi = mid; }
    int end = lo;
    float acc = 0.0f;
    int i = start;
    for (; i + 3 < end; i += 4) {
        acc += (bf2f((uint)h2[(size_t)(i + 0) * DIM + f]) + bf2f((uint)h2[(size_t)(i + 1) * DIM + f]))
             + (bf2f((uint)h2[(size_t)(i + 2) * DIM + f]) + bf2f((uint)h2[(size_t)(i + 3) * DIM + f]));
    }
    for (; i < end; ++i) acc += bf2f((uint)h2[(size_t)i * DIM + f]);
    float factor = 16.0f * (float)NODES / *norm_sum;   // sqrt(256) / mean row norm
    out[(size_t)g * DIM + f] = acc * factor;
}

extern "C" void kernel_launch(void* const* d_in, const int* in_sizes, int n_in,
                              void* d_out, int out_size, void* d_ws, size_t ws_size,
                              hipStream_t stream) {
    const float* x  = (const float*)d_in[0];
    const float* W1 = (const float*)d_in[1];
    const float* b1 = (const float*)d_in[2];
    const float* W2 = (const float*)d_in[3];
    const float* b2 = (const float*)d_in[4];
    const int* src = (const int*)d_in[5];
    const int* dst = (const int*)d_in[6];
    const int* n2g = (const int*)d_in[7];
    float* out = (float*)d_out;

    char* ws = (char*)d_ws;
    size_t off = 0;
    auto alloc = [&](size_t bytes) {
        char* p = ws + off;
        off = (off + bytes + 255) & ~(size_t)255;
        return p;
    };
    uint* histIn    = (uint*)alloc((size_t)HBLOCKS * 2 * HALF_W * 4);  // 25.6 MB
    uint* histOut   = (uint*)alloc((size_t)HBLOCKS * 2 * HALF_W * 4);  // 25.6 MB
    int* deg_in     = (int*)alloc(NODES * 4);
    float* out_norm = (float*)alloc(NODES * 4);
    float* in_norm  = (float*)alloc(NODES * 4);
    int* row_start  = (int*)alloc((NODES + 1) * 4);
    int* src_sorted = (int*)alloc(EDGES * 4);
    int* block_sums = (int*)alloc(RB * 4);
    float* norm_sum = (float*)alloc(4);
    ushort* W1T     = (ushort*)alloc((size_t)DIM * FIN * 2);   // [256][128]
    ushort* W2T     = (ushort*)alloc((size_t)DIM * DIM * 2);   // [256][256]
    ushort* xs      = (ushort*)alloc((size_t)NODES * FIN * 2); // prescaled input
    ushort* h1s     = (ushort*)alloc((size_t)PAD_M * DIM * 2); // layer-1 out (pre-scaled)
    ushort* h2      = (ushort*)alloc((size_t)PAD_M * DIM * 2); // layer-2 out (own buffer:
                                                               // fused L2 reads h1s while writing h2)

    // CSR build + prep: 4 dispatches, zero global atomics.
    hist2_kernel<<<2 * HBLOCKS, 256, 0, stream>>>(src, dst, histIn, histOut, norm_sum);
    reduce_hist_kernel<<<RB, 256, 0, stream>>>(histIn, histOut, deg_in, in_norm, out_norm, block_sums);
    scanfinal_prep_kernel<<<RB + PRESCALE_BLOCKS + FIN * DIM / 256 + DIM * DIM / 256, 256, 0, stream>>>(
        deg_in, block_sums, row_start, x, out_norm, xs, W1, W1T, W2, W2T);
    scatter_lds_kernel<<<HBLOCKS, 256, 0, stream>>>(src, dst, histIn, row_start, src_sorted);

    // Layer 1 fused: gather xs -> LDS tile -> MFMA W1 -> h1s (relu, pre-scaled by out_norm)
    gemm_agg_kernel<FIN, 0><<<PAD_M / 64, 256, 0, stream>>>(
        xs, row_start, src_sorted, in_norm, W1T, b1, h1s, out_norm, norm_sum, NODES);

    // Layer 2 fused: gather h1s -> LDS tile -> MFMA W2 -> h2 + row-norm accumulation
    gemm_agg_kernel<DIM, 1><<<PAD_M / 64, 256, 0, stream>>>(
        h1s, row_start, src_sorted, in_norm, W2T, b2, h2, nullptr, norm_sum, NODES);

    // Per-graph sum-pool with inline factor.
    pool_kernel<<<GRAPHS, 256, 0, stream>>>(h2, n2g, norm_sum, out);
}

// Round 12
// 265.297 us; speedup vs baseline: 1.2328x; 1.2328x over previous
//
#include <hip/hip_runtime.h>

#define NODES 50000
#define EDGES 800000
#define FIN 128
#define DIM 256
#define GRAPHS 256
#define PAD_M 50048   // 782 * 64
#define PRESCALE_BLOCKS (NODES * FIN / 4 / 256) // 6250 exact
#define HBLOCKS 256                             // histogram copies / edge chunks
#define CHUNK (EDGES / HBLOCKS)                 // 3125 edges per block, exact
#define HALF_N 25000                            // nodes per LDS half
#define HALF_W 12500                            // u32 words per half (2 nodes/u32)
#define RB 98                                   // reduce/scan blocks (512 nodes each)

typedef short short8 __attribute__((ext_vector_type(8)));
typedef float f32x4 __attribute__((ext_vector_type(4)));

__device__ __forceinline__ float bf2f(uint u) { return __uint_as_float(u << 16); }
__device__ __forceinline__ ushort f2bf(float f) {
    uint b = __float_as_uint(f);
    return (ushort)((b + 0x7FFF + ((b >> 16) & 1)) >> 16);
}

// Both histograms in ONE dispatch: blocks [0,256) dst->histIn, [256,512) src->histOut.
// Also zeroes norm_sum for this launch. Streaming dump, no global atomics.
__global__ __launch_bounds__(256) void hist2_kernel(const int* __restrict__ src,
                                                    const int* __restrict__ dst,
                                                    uint* __restrict__ histIn,
                                                    uint* __restrict__ histOut,
                                                    float* __restrict__ norm_sum) {
    __shared__ uint cur[HALF_W];
    if (blockIdx.x == 0 && threadIdx.x == 0) *norm_sum = 0.0f;
    int b = blockIdx.x & 255, tid = threadIdx.x;
    const int* idx = (blockIdx.x < HBLOCKS) ? dst : src;
    uint* histG    = (blockIdx.x < HBLOCKS) ? histIn : histOut;
    int base = b * CHUNK;
    for (int half = 0; half < 2; ++half) {
        for (int j = tid; j < HALF_W; j += 256) cur[j] = 0;
        __syncthreads();
        int lo = half * HALF_N;
        for (int e = base + tid; e < base + CHUNK; e += 256) {
            int local = idx[e] - lo;
            if ((unsigned)local < (unsigned)HALF_N)
                atomicAdd(&cur[local >> 1], 1u << ((local & 1) * 16));
        }
        __syncthreads();
        uint* dstp = histG + (size_t)b * (2 * HALF_W) + half * HALF_W;
        for (int j = tid; j < HALF_W; j += 256) dstp[j] = cur[j];
        __syncthreads();
    }
}

// Sum the 256 copies -> deg_in / norms; in-place transform histIn into per-block
// EXCLUSIVE prefixes (packed u16); emit per-512-node block sums.
__global__ __launch_bounds__(256) void reduce_hist_kernel(uint* __restrict__ histIn,
                                                          const uint* __restrict__ histOut,
                                                          int* __restrict__ deg_in,
                                                          float* __restrict__ in_norm,
                                                          float* __restrict__ out_norm,
                                                          int* __restrict__ block_sums) {
    __shared__ int red[4];
    int t32 = blockIdx.x * 256 + threadIdx.x;
    uint lo = 0, hi = 0;
    if (t32 < 2 * HALF_W) {
#pragma unroll 4
        for (int c = 0; c < HBLOCKS; ++c) {
            size_t a = (size_t)c * (2 * HALF_W) + t32;
            uint u = histIn[a];
            histIn[a] = lo | (hi << 16);       // exclusive prefix over blocks
            lo += u & 0xFFFFu;
            hi += u >> 16;
        }
        uint olo = 0, ohi = 0;
#pragma unroll 4
        for (int c = 0; c < HBLOCKS; ++c) {
            uint u = histOut[(size_t)c * (2 * HALF_W) + t32];
            olo += u & 0xFFFFu;
            ohi += u >> 16;
        }
        int n0 = 2 * t32;
        deg_in[n0]     = (int)lo;
        deg_in[n0 + 1] = (int)hi;
        in_norm[n0]      = rsqrtf(fmaxf((float)lo, 1.0f));
        in_norm[n0 + 1]  = rsqrtf(fmaxf((float)hi, 1.0f));
        out_norm[n0]     = rsqrtf(fmaxf((float)olo, 1.0f));
        out_norm[n0 + 1] = rsqrtf(fmaxf((float)ohi, 1.0f));
    }
    int s = (int)(lo + hi);
    int wave = threadIdx.x >> 6, lane = threadIdx.x & 63;
#pragma unroll
    for (int off = 32; off > 0; off >>= 1) s += __shfl_down(s, off);
    if (lane == 0) red[wave] = s;
    __syncthreads();
    if (threadIdx.x == 0) block_sums[blockIdx.x] = red[0] + red[1] + red[2] + red[3];
}

// scan-final with inline (redundant per-block) scan of the 98 block sums.
__global__ __launch_bounds__(256) void scanfinal_kernel(const int* __restrict__ deg,
                                                        const int* __restrict__ block_sums,
                                                        int* __restrict__ row_start) {
    __shared__ int s[256];
    int b = blockIdx.x, t = threadIdx.x;
    s[t] = (t < RB) ? block_sums[t] : 0;
    __syncthreads();
#pragma unroll
    for (int off = 1; off < 256; off <<= 1) {
        int u = (t >= off) ? s[t - off] : 0;
        __syncthreads();
        s[t] += u;
        __syncthreads();
    }
    int block_off = (b == 0) ? 0 : s[b - 1];
    if (b == 0 && t == 0) row_start[NODES] = s[RB - 1];   // total = EDGES
    __syncthreads();
    int i0 = b * 512 + 2 * t;
    int v0 = (i0 < NODES) ? deg[i0] : 0;
    int v1 = (i0 + 1 < NODES) ? deg[i0 + 1] : 0;
    int pair = v0 + v1;
    s[t] = pair;
    __syncthreads();
#pragma unroll
    for (int off = 1; off < 256; off <<= 1) {
        int u = (t >= off) ? s[t - off] : 0;
        __syncthreads();
        s[t] += u;
        __syncthreads();
    }
    int excl = block_off + s[t] - pair;
    if (i0 < NODES) row_start[i0] = excl;
    if (i0 + 1 < NODES) row_start[i0 + 1] = excl + v0;
}

// Merged dispatch: blocks [0,256) = LDS-cursor scatter (1 block/CU, low TLP);
// blocks [256, 6890) = prep (xs prescale | W1T | W2T) filling the idle CUs.
// Scatter needs row_start (prev dispatch); prep needs out_norm (2 dispatches ago).
__global__ __launch_bounds__(256) void scatter_prep_kernel(const int* __restrict__ src,
                                                           const int* __restrict__ dst,
                                                           const uint* __restrict__ histIn,
                                                           const int* __restrict__ row_start,
                                                           int* __restrict__ src_sorted,
                                                           const float* __restrict__ x,
                                                           const float* __restrict__ out_norm,
                                                           ushort* __restrict__ xs,
                                                           const float* __restrict__ W1,
                                                           ushort* __restrict__ W1T,
                                                           const float* __restrict__ W2,
                                                           ushort* __restrict__ W2T) {
    __shared__ uint cur[HALF_W];
    int tid = threadIdx.x;
    if (blockIdx.x < HBLOCKS) {
        int b = blockIdx.x;
        int base = b * CHUNK;
        for (int half = 0; half < 2; ++half) {
            const uint* offp = histIn + (size_t)b * (2 * HALF_W) + half * HALF_W;
            for (int j = tid; j < HALF_W; j += 256) cur[j] = offp[j];
            __syncthreads();
            int lo = half * HALF_N;
            for (int e = base + tid; e < base + CHUNK; e += 256) {
                int d = dst[e];
                int local = d - lo;
                if ((unsigned)local < (unsigned)HALF_N) {
                    int sel = (local & 1) * 16;
                    uint old = atomicAdd(&cur[local >> 1], 1u << sel);
                    int pos = row_start[d] + (int)((old >> sel) & 0xFFFFu);
                    src_sorted[pos] = src[e];
                }
            }
            __syncthreads();
        }
    } else {
        int bb = blockIdx.x - HBLOCKS;
        if (bb < PRESCALE_BLOCKS) {
            int i = bb * 256 + tid;                   // < NODES*FIN/4
            int row = i >> 5;                         // FIN/4 = 32 float4 per row
            float on = out_norm[row];
            float4 v = ((const float4*)x)[i];
            ushort4 o;
            o.x = f2bf(v.x * on); o.y = f2bf(v.y * on);
            o.z = f2bf(v.z * on); o.w = f2bf(v.w * on);
            ((ushort4*)xs)[i] = o;
        } else if (bb < PRESCALE_BLOCKS + FIN * DIM / 256) {
            int i = (bb - PRESCALE_BLOCKS) * 256 + tid;   // < 32768
            int n = i >> 7, k = i & 127;
            W1T[i] = f2bf(W1[(size_t)k * DIM + n]);
        } else {
            int i = (bb - PRESCALE_BLOCKS - FIN * DIM / 256) * 256 + tid;  // < 65536
            int n = i >> 8, k = i & 255;
            W2T[i] = f2bf(W2[(size_t)k * DIM + n]);
        }
    }
}

// Gather-sum aggregation, bf16 in/out, fp32 accumulate. One wave per node.
// 8-edge unroll, branchless masked tail (measured gather-stream roofline form).
template<int D>
__global__ __launch_bounds__(256) void agg_kernel(const ushort* __restrict__ in,
                                                  const int* __restrict__ row_start,
                                                  const int* __restrict__ src_sorted,
                                                  const float* __restrict__ in_norm,
                                                  ushort* __restrict__ out) {
    constexpr int VPL = D / 64;       // bf16 per lane (2 or 4)
    constexpr int NU = VPL / 2;       // uint loads per lane
    int wave = threadIdx.x >> 6, lane = threadIdx.x & 63;
    int node = blockIdx.x * 4 + wave;
    if (node >= NODES) return;
    int off = lane * VPL;
    int e0 = row_start[node], e1 = row_start[node + 1];
    float acc[VPL] = {};
    int niter = (e1 - e0 + 7) >> 3;
    for (int it = 0; it < niter; ++it) {
        int eb = e0 + it * 8;
        int idx[8];
#pragma unroll
        for (int j = 0; j < 8; ++j) idx[j] = src_sorted[min(eb + j, e1 - 1)];
        uint u[8][NU];
#pragma unroll
        for (int j = 0; j < 8; ++j) {
            const uint* p = (const uint*)(in + (size_t)idx[j] * D + off);
#pragma unroll
            for (int q = 0; q < NU; ++q) u[j][q] = p[q];
        }
#pragma unroll
        for (int j = 0; j < 8; ++j) {
            uint ok = (eb + j < e1) ? 0xFFFFFFFFu : 0u;
#pragma unroll
            for (int q = 0; q < NU; ++q) {
                uint uu = u[j][q] & ok;
                acc[2*q]   += bf2f(uu & 0xFFFFu);
                acc[2*q+1] += bf2f(uu >> 16);
            }
        }
    }
    float inn = in_norm[node];
    uint* po = (uint*)(out + (size_t)node * D + off);
#pragma unroll
    for (int q = 0; q < NU; ++q) {
        uint lo = f2bf(acc[2*q] * inn);
        uint hi = f2bf(acc[2*q+1] * inn);
        po[q] = lo | (hi << 16);
    }
}

// MFMA GEMM: C[M,256] = A[M,K](bf16) @ W + bias. WT[256][K] bf16, no LDS staging.
// MODE 0: out bf16 = relu(acc+bias)*scale[row]     (h1s, pre-scaled for next gather)
// MODE 1: out bf16 = acc+bias, fused row-L2-norm accumulation into norm_sum
template<int K, int MODE>
__global__ __launch_bounds__(256) void gemm_mfma_kernel(const ushort* __restrict__ A,
                                                        const ushort* __restrict__ WT,
                                                        const float* __restrict__ bias,
                                                        ushort* __restrict__ Cout,
                                                        const float* __restrict__ scale,
                                                        float* __restrict__ norm_sum,
                                                        int M) {
    __shared__ float rowsq[4][64];
    int lane = threadIdx.x & 63, wave = threadIdx.x >> 6;
    int m0 = blockIdx.x * 64, n0 = wave * 64;
    int ll = lane & 15, lh = lane >> 4;
    f32x4 acc[4][4] = {};
    const ushort* Ab = A  + (size_t)(m0 + ll) * K + lh * 8;
    const ushort* Bb = WT + (size_t)(n0 + ll) * K + lh * 8;
#pragma unroll
    for (int k0 = 0; k0 < K; k0 += 32) {
        short8 a[4], b[4];
#pragma unroll
        for (int mi = 0; mi < 4; ++mi) a[mi] = *(const short8*)(Ab + (size_t)mi * 16 * K + k0);
#pragma unroll
        for (int ni = 0; ni < 4; ++ni) b[ni] = *(const short8*)(Bb + (size_t)ni * 16 * K + k0);
#pragma unroll
        for (int mi = 0; mi < 4; ++mi)
#pragma unroll
            for (int ni = 0; ni < 4; ++ni)
                acc[mi][ni] = __builtin_amdgcn_mfma_f32_16x16x32_bf16(a[mi], b[ni], acc[mi][ni], 0, 0, 0);
    }
#pragma unroll
    for (int mi = 0; mi < 4; ++mi) {
#pragma unroll
        for (int r = 0; r < 4; ++r) {
            int row = m0 + mi * 16 + lh * 4 + r;
            float sc = (MODE == 0 && row < M) ? scale[row] : 1.0f;
            float p = 0.0f;
#pragma unroll
            for (int ni = 0; ni < 4; ++ni) {
                int col = n0 + ni * 16 + ll;
                float v = acc[mi][ni][r] + bias[col];
                if (MODE == 0) v = fmaxf(v, 0.0f) * sc;
                else p += v * v;
                if (row < M) Cout[(size_t)row * DIM + col] = f2bf(v);
            }
            if (MODE == 1) {
#pragma unroll
                for (int m = 1; m < 16; m <<= 1) p += __shfl_xor(p, m);
                if (ll == 0) rowsq[wave][mi * 16 + lh * 4 + r] = p;
            }
        }
    }
    if (MODE == 1) {
        __syncthreads();
        if (threadIdx.x < 64) {
            int lr = threadIdx.x;
            float s = rowsq[0][lr] + rowsq[1][lr] + rowsq[2][lr] + rowsq[3][lr];
            float l = (m0 + lr < M) ? sqrtf(s) : 0.0f;
#pragma unroll
            for (int m = 32; m > 0; m >>= 1) l += __shfl_down(l, m);
            if (lr == 0) atomicAdd(norm_sum, l);
        }
    }
}

// One block per graph (n2g is sorted): binary-search node range, no atomics.
__global__ __launch_bounds__(256) void pool_kernel(const ushort* __restrict__ h2,
                                                   const int* __restrict__ n2g,
                                                   const float* __restrict__ norm_sum,
                                                   float* __restrict__ out) {
    int g = blockIdx.x, f = threadIdx.x;
    int lo = 0, hi = NODES;
    while (lo < hi) { int mid = (lo + hi) >> 1; if (n2g[mid] < g) lo = mid + 1; else hi = mid; }
    int start = lo;
    hi = NODES;
    while (lo < hi) { int mid = (lo + hi) >> 1; if (n2g[mid] < g + 1) lo = mid + 1; else hi = mid; }
    int end = lo;
    float acc = 0.0f;
    int i = start;
    for (; i + 3 < end; i += 4) {
        acc += (bf2f((uint)h2[(size_t)(i + 0) * DIM + f]) + bf2f((uint)h2[(size_t)(i + 1) * DIM + f]))
             + (bf2f((uint)h2[(size_t)(i + 2) * DIM + f]) + bf2f((uint)h2[(size_t)(i + 3) * DIM + f]));
    }
    for (; i < end; ++i) acc += bf2f((uint)h2[(size_t)i * DIM + f]);
    float factor = 16.0f * (float)NODES / *norm_sum;   // sqrt(256) / mean row norm
    out[(size_t)g * DIM + f] = acc * factor;
}

extern "C" void kernel_launch(void* const* d_in, const int* in_sizes, int n_in,
                              void* d_out, int out_size, void* d_ws, size_t ws_size,
                              hipStream_t stream) {
    const float* x  = (const float*)d_in[0];
    const float* W1 = (const float*)d_in[1];
    const float* b1 = (const float*)d_in[2];
    const float* W2 = (const float*)d_in[3];
    const float* b2 = (const float*)d_in[4];
    const int* src = (const int*)d_in[5];
    const int* dst = (const int*)d_in[6];
    const int* n2g = (const int*)d_in[7];
    float* out = (float*)d_out;

    char* ws = (char*)d_ws;
    size_t off = 0;
    auto alloc = [&](size_t bytes) {
        char* p = ws + off;
        off = (off + bytes + 255) & ~(size_t)255;
        return p;
    };
    uint* histIn    = (uint*)alloc((size_t)HBLOCKS * 2 * HALF_W * 4);  // 25.6 MB
    uint* histOut   = (uint*)alloc((size_t)HBLOCKS * 2 * HALF_W * 4);  // 25.6 MB
    int* deg_in     = (int*)alloc(NODES * 4);
    float* out_norm = (float*)alloc(NODES * 4);
    float* in_norm  = (float*)alloc(NODES * 4);
    int* row_start  = (int*)alloc((NODES + 1) * 4);
    int* src_sorted = (int*)alloc(EDGES * 4);
    int* block_sums = (int*)alloc(RB * 4);
    float* norm_sum = (float*)alloc(4);
    ushort* W1T     = (ushort*)alloc((size_t)DIM * FIN * 2);   // [256][128]
    ushort* W2T     = (ushort*)alloc((size_t)DIM * DIM * 2);   // [256][256]
    // Aliased feature regions (R10-verified):
    // P0: xs [PAD_M][128] bf16 -> low half of A2 | P1: A1 [PAD_M][128] -> high half of A2
    // H : h1s [PAD_M][256] bf16 -> reused as h2 (agg2 consumed h1s before gemm2 writes)
    ushort* xs  = (ushort*)alloc((size_t)PAD_M * FIN * 2);
    ushort* A1  = (ushort*)alloc((size_t)PAD_M * FIN * 2);
    ushort* h1s = (ushort*)alloc((size_t)PAD_M * DIM * 2);
    ushort* A2 = xs;          // [PAD_M][256] bf16, overlays P0+P1
    ushort* h2 = h1s;         // [PAD_M][256] bf16, overlays H

    // CSR build + prep: 4 dispatches, zero global atomics, prep overlapped w/ scatter.
    hist2_kernel<<<2 * HBLOCKS, 256, 0, stream>>>(src, dst, histIn, histOut, norm_sum);
    reduce_hist_kernel<<<RB, 256, 0, stream>>>(histIn, histOut, deg_in, in_norm, out_norm, block_sums);
    scanfinal_kernel<<<RB, 256, 0, stream>>>(deg_in, block_sums, row_start);
    scatter_prep_kernel<<<HBLOCKS + PRESCALE_BLOCKS + FIN * DIM / 256 + DIM * DIM / 256, 256, 0, stream>>>(
        src, dst, histIn, row_start, src_sorted, x, out_norm, xs, W1, W1T, W2, W2T);

    // Layer 1
    agg_kernel<FIN><<<(NODES + 3) / 4, 256, 0, stream>>>(xs, row_start, src_sorted, in_norm, A1);
    gemm_mfma_kernel<FIN, 0><<<PAD_M / 64, 256, 0, stream>>>(A1, W1T, b1, h1s, out_norm, norm_sum, NODES);

    // Layer 2 (gemm2 fuses row-norm accumulation, writes bf16 h2)
    agg_kernel<DIM><<<(NODES + 3) / 4, 256, 0, stream>>>(h1s, row_start, src_sorted, in_norm, A2);
    gemm_mfma_kernel<DIM, 1><<<PAD_M / 64, 256, 0, stream>>>(A2, W2T, b2, h2, nullptr, norm_sum, NODES);

    // Per-graph sum-pool with inline factor.
    pool_kernel<<<GRAPHS, 256, 0, stream>>>(h2, n2g, norm_sum, out);
}